// Round 8
// baseline (585.579 us; speedup 1.0000x reference)
//
#include <hip/hip_runtime.h>
#include <hip/hip_bf16.h>
#include <math.h>

#define BETA_F 0.9f
#define THR1_F 1.0f
#define THR2_F 0.8f

typedef __attribute__((ext_vector_type(8))) short bf16x8;
typedef __attribute__((ext_vector_type(4))) float f32x4;

__device__ __forceinline__ void gload_lds16(const void* g, void* l) {
    __builtin_amdgcn_global_load_lds(
        (const __attribute__((address_space(1))) void*)g,
        (__attribute__((address_space(3))) void*)l, 16, 0, 0);
}

__device__ __forceinline__ ushort f2bf(float f) {
    __hip_bfloat16 h = __float2bfloat16(f);
    return *(ushort*)&h;
}
__device__ __forceinline__ float bf2f(ushort u) {
    __hip_bfloat16 h;
    *(ushort*)&h = u;
    return __bfloat162float(h);
}

// ---------------- init: delay factors + state zeroing ----------------
__global__ void k_init(const float* __restrict__ cd1, const float* __restrict__ v1,
                       const float* __restrict__ cd2, const float* __restrict__ v2,
                       float* __restrict__ df1, float* __restrict__ df2,
                       float* __restrict__ p1, float* __restrict__ p2,
                       float* __restrict__ acc2,
                       int I, int H, int BI, int BH) {
    float vc1 = fminf(fmaxf(v1[0], 0.0f), 0.999f);
    float vc2 = fminf(fmaxf(v2[0], 0.0f), 0.999f);
    double g1 = 1.0 / sqrt(1.0 - (double)vc1 * (double)vc1);
    double g2 = 1.0 / sqrt(1.0 - (double)vc2 * (double)vc2);
    int total = I + H + BI + BH + BH;
    for (int idx = blockIdx.x * blockDim.x + threadIdx.x; idx < total;
         idx += gridDim.x * blockDim.x) {
        if (idx < I) {
            df1[idx] = (float)exp(-(g1 * fabs((double)cd1[idx]) * (double)vc1));
        } else if (idx < I + H) {
            int j = idx - I;
            df2[j] = (float)exp(-(g2 * fabs((double)cd2[j]) * (double)vc2));
        } else if (idx < I + H + BI) {
            p1[idx - I - H] = 0.0f;
        } else if (idx < I + H + BI + BH) {
            p2[idx - I - H - BI] = 0.0f;
        } else {
            acc2[idx - I - H - BI - BH] = 0.0f;
        }
    }
}

// ---------------- time-weight table (normalized) ----------------
__global__ void k_tw(const float* __restrict__ v1, float* __restrict__ tw, int T) {
    __shared__ float sh[256];
    float vc = fminf(fmaxf(v1[0], 0.0f), 0.999f);
    double g = 1.0 / sqrt(1.0 - (double)vc * (double)vc);
    int t = threadIdx.x;
    float val = 0.0f;
    if (t < T) val = (float)exp(-(g - 1.0) * (double)t);
    sh[t] = val;
    __syncthreads();
    for (int s = 128; s > 0; s >>= 1) {
        if (t < s) sh[t] += sh[t + s];
        __syncthreads();
    }
    float sum = sh[0];
    if (t < T) tw[t] = val / sum;
}

// ------ split W1 into hi/lo bf16, concatenated along K: Bcat[N][2I] --------
__global__ void k_wsplit(const float* __restrict__ W, ushort* __restrict__ bcat,
                         int n, int I) {
    int i = blockIdx.x * blockDim.x + threadIdx.x;
    if (i >= n) return;
    float w = W[i];
    ushort h = f2bf(w);
    float hf = bf2f(h);
    ushort l = f2bf(w - hf);
    int row = i / I, k = i - row * I;
    bcat[(size_t)row * 2 * I + k] = h;
    bcat[(size_t)row * 2 * I + I + k] = l;
}

// ---------------- layer-1 LIF over a chunk of timesteps (bf16 spikes) -------
__global__ void k_lif1(const float* __restrict__ x, const float* __restrict__ df1,
                       float* __restrict__ p1, ushort* __restrict__ s1,
                       int Bsz, int T, int I, int t0, int TC) {
    int idx = blockIdx.x * blockDim.x + threadIdx.x;  // b*I + i
    if (idx >= Bsz * I) return;
    int b = idx / I;
    int i = idx - b * I;
    float df = df1[i];
    float p = p1[idx];
    const float* xp = x + ((size_t)b * T + t0) * I + i;
    size_t strideS = (size_t)Bsz * I;
    for (int t = 0; t < TC; ++t) {
        float xv = xp[(size_t)t * I];
        float pn = __fadd_rn(__fmul_rn(p, BETA_F), __fmul_rn(xv, df));
        bool spk = pn > THR1_F;
        s1[(size_t)t * strideS + idx] = spk ? (ushort)0x3F80 : (ushort)0;
        p = spk ? 0.0f : pn;
    }
    p1[idx] = p;
}

// ---------------- layer-2 LIF + weighted spike accumulation ----------------
__global__ void k_lif2(const float* __restrict__ h, const float* __restrict__ df2,
                       const float* __restrict__ tw, float* __restrict__ p2,
                       float* __restrict__ acc2, int Bsz, int H, int t0, int TC) {
    int idx = blockIdx.x * blockDim.x + threadIdx.x;  // b*H + j
    if (idx >= Bsz * H) return;
    int j = idx % H;
    float df = df2[j];
    float p = p2[idx];
    float acc = acc2[idx];
    size_t strideH = (size_t)Bsz * H;
    for (int t = 0; t < TC; ++t) {
        float hv = h[(size_t)t * strideH + idx];
        float pn = __fadd_rn(__fmul_rn(p, BETA_F), __fmul_rn(hv, df));
        bool spk = pn > THR2_F;
        if (spk) acc += tw[t0 + t];
        p = spk ? 0.0f : pn;
    }
    p2[idx] = p;
    acc2[idx] = acc;
}

// ---------------- MFMA GEMM: C = A(bf16, K1 wrap) @ Bcat^T + bias ----------
// A: [M][K1] bf16 spikes; Bcat: [N][2*K1] (hi|lo); effective K' = 2*K1.
// Tile 256x256, BK=64, 512 threads = 8 waves (2M x 4N), wave tile 128x64.
// Double-buffered LDS (128 KiB), depth-2 prefetch with COUNTED vmcnt(8)
// (loads stay in flight across barriers - T3/T4), XOR chunk swizzle (T2,
// conflict-free), setprio (T5), bijective XCD block swizzle (T1).
__global__ __launch_bounds__(512, 2)
void k_gemm_mfma(const ushort* __restrict__ A, const ushort* __restrict__ Bc,
                 const float* __restrict__ bias, float* __restrict__ C,
                 int N, int K1, int gx) {
    __shared__ ushort As[2][16384];   // 256 rows x 64 (bf16), 8 chunks of 16B/row
    __shared__ ushort Bs[2][16384];
    int nwg = gridDim.x;
    int lin = blockIdx.x;
    int cpx = nwg >> 3;                        // nwg % 8 == 0 by construction
    int swz = (lin & 7) * cpx + (lin >> 3);
    int bx = swz % gx, by = swz / gx;
    int mBase = by * 256, nBase = bx * 256;
    int tid = threadIdx.x;
    int wid = tid >> 6, lane = tid & 63;
    int K2 = 2 * K1;

    // ---- staging: linear LDS dest, inverse-swizzled global source ----
    // LDS[row][phys] holds global chunk (phys ^ (row&7)); 4 segments of 64 rows.
    int srow = tid >> 3;                       // 0..63 (row within segment)
    int p = tid & 7;                           // physical 16B chunk
    int lch = (p ^ (srow & 7)) * 8;            // logical chunk elem offset
    const ushort* aSeg[4];
    const ushort* bSeg[4];
#pragma unroll
    for (int s = 0; s < 4; s++) {
        aSeg[s] = A + (size_t)(mBase + s * 64 + srow) * K1 + lch;
        bSeg[s] = Bc + (size_t)(nBase + s * 64 + srow) * K2 + lch;
    }
    int ldsOff = tid * 8;                      // ushort offset within segment

    auto stage = [&](int buf, int kt) {
        int k0 = kt << 6;
        int aK = k0 & (K1 - 1);                // A wraps: hi half = lo half source
#pragma unroll
        for (int s = 0; s < 4; s++)
            gload_lds16(aSeg[s] + aK, &As[buf][s * 4096 + ldsOff]);
#pragma unroll
        for (int s = 0; s < 4; s++)
            gload_lds16(bSeg[s] + k0, &Bs[buf][s * 4096 + ldsOff]);
    };

    // ---- fragment read offsets (swizzle matches staging) ----
    int wr = wid >> 2, wc = wid & 3;           // 2 x 4 wave grid
    int hi = lane >> 4, l15 = lane & 15;
    int sw7 = l15 & 7;                         // row&7 for all frag rows
    int aRow = (wr * 128 + l15) * 64;
    int bRow = (wc * 64 + l15) * 64;
    int aoff0 = aRow + ((hi ^ sw7) * 8);       // k-half 0: chunks 0..3
    int aoff1 = aRow + (((4 + hi) ^ sw7) * 8); // k-half 1: chunks 4..7
    int boff0 = bRow + ((hi ^ sw7) * 8);
    int boff1 = bRow + (((4 + hi) ^ sw7) * 8);

    f32x4 acc[8][4];
#pragma unroll
    for (int f = 0; f < 8; f++)
#pragma unroll
        for (int j = 0; j < 4; j++) acc[f][j] = (f32x4)(0.0f);

    auto compute = [&](int cur) {
        bf16x8 af[8], bf[4];
        // k-half 0
#pragma unroll
        for (int f = 0; f < 8; f++) af[f] = *(const bf16x8*)&As[cur][aoff0 + f * 1024];
#pragma unroll
        for (int j = 0; j < 4; j++) bf[j] = *(const bf16x8*)&Bs[cur][boff0 + j * 1024];
        __builtin_amdgcn_s_setprio(1);
#pragma unroll
        for (int f = 0; f < 8; f++)
#pragma unroll
            for (int j = 0; j < 4; j++)
                acc[f][j] = __builtin_amdgcn_mfma_f32_16x16x32_bf16(af[f], bf[j],
                                                                    acc[f][j], 0, 0, 0);
        __builtin_amdgcn_s_setprio(0);
        // k-half 1
#pragma unroll
        for (int f = 0; f < 8; f++) af[f] = *(const bf16x8*)&As[cur][aoff1 + f * 1024];
#pragma unroll
        for (int j = 0; j < 4; j++) bf[j] = *(const bf16x8*)&Bs[cur][boff1 + j * 1024];
        __builtin_amdgcn_s_setprio(1);
#pragma unroll
        for (int f = 0; f < 8; f++)
#pragma unroll
            for (int j = 0; j < 4; j++)
                acc[f][j] = __builtin_amdgcn_mfma_f32_16x16x32_bf16(af[f], bf[j],
                                                                    acc[f][j], 0, 0, 0);
        __builtin_amdgcn_s_setprio(0);
    };

    int NT = K2 >> 6;                          // 32 K-tiles of 64
    stage(0, 0);
    stage(1, 1);
    for (int kt = 0; kt < NT - 1; ++kt) {
        // counted wait: newest 8 loads (tile kt+1) stay in flight; tile kt done.
        asm volatile("s_waitcnt vmcnt(8)\ns_barrier" ::: "memory");
        compute(kt & 1);
        asm volatile("s_barrier" ::: "memory");  // all waves done reading buf
        if (kt + 2 < NT) stage(kt & 1, kt + 2);
    }
    asm volatile("s_waitcnt vmcnt(0)\ns_barrier" ::: "memory");
    compute((NT - 1) & 1);

    // C/D layout (m89-verified): col = lane&15, row = (lane>>4)*4 + reg
    int crow0 = mBase + wr * 128 + hi * 4;
    int ccol0 = nBase + wc * 64 + l15;
#pragma unroll
    for (int f = 0; f < 8; f++) {
#pragma unroll
        for (int j = 0; j < 4; j++) {
            int col = ccol0 + j * 16;
            float bv = bias[col];
#pragma unroll
            for (int r = 0; r < 4; r++) {
                int row = crow0 + f * 16 + r;
                C[(size_t)row * N + col] = acc[f][j][r] + bv;
            }
        }
    }
}

// ---------------- small f32 GEMM (split-K): P[z] = A @ B^T slice ------------
__global__ __launch_bounds__(256)
void k_gemm64(const float* __restrict__ A, const float* __restrict__ Bm,
              float* __restrict__ P, int M, int N, int K, int KS) {
    __shared__ float As[16][68];
    __shared__ float Bs[16][68];
    int tid = threadIdx.x;
    int mBase = blockIdx.y * 64, nBase = blockIdx.x * 64;
    int k0 = blockIdx.z * KS;
    int lr = tid >> 2, lk = (tid & 3) * 4;
    int ty = tid >> 4, tx = tid & 15;
    float acc[4][4];
#pragma unroll
    for (int i = 0; i < 4; i++)
#pragma unroll
        for (int j = 0; j < 4; j++) acc[i][j] = 0.0f;
    const float* Ap = A + (size_t)(mBase + lr) * K + k0 + lk;
    const float* Bp = Bm + (size_t)(nBase + lr) * K + k0 + lk;
    for (int k = 0; k < KS; k += 16) {
        float4 av = *(const float4*)(Ap + k);
        float4 bv = *(const float4*)(Bp + k);
        __syncthreads();
        As[lk + 0][lr] = av.x; As[lk + 1][lr] = av.y;
        As[lk + 2][lr] = av.z; As[lk + 3][lr] = av.w;
        Bs[lk + 0][lr] = bv.x; Bs[lk + 1][lr] = bv.y;
        Bs[lk + 2][lr] = bv.z; Bs[lk + 3][lr] = bv.w;
        __syncthreads();
#pragma unroll
        for (int kk = 0; kk < 16; ++kk) {
            float4 a4 = *(const float4*)&As[kk][ty * 4];
            float4 b4 = *(const float4*)&Bs[kk][tx * 4];
            float aa[4] = {a4.x, a4.y, a4.z, a4.w};
            float bb[4] = {b4.x, b4.y, b4.z, b4.w};
#pragma unroll
            for (int i = 0; i < 4; i++)
#pragma unroll
                for (int j = 0; j < 4; j++)
                    acc[i][j] = fmaf(aa[i], bb[j], acc[i][j]);
        }
    }
#pragma unroll
    for (int i = 0; i < 4; i++)
#pragma unroll
        for (int j = 0; j < 4; j++)
            P[((size_t)blockIdx.z * M + mBase + ty * 4 + i) * N + nBase + tx * 4 + j] =
                acc[i][j];
}

// ---------------- final reduce + epilogue ----------------
__global__ void k_fin(const float* __restrict__ P, const float* __restrict__ b2,
                      const float* __restrict__ scale, const float* __restrict__ bias2,
                      float* __restrict__ out, int M, int N, int Z) {
    int i = blockIdx.x * blockDim.x + threadIdx.x;
    if (i >= M * N) return;
    float s = 0.0f;
    for (int z = 0; z < Z; ++z) s += P[(size_t)z * M * N + i];
    int col = i % N;
    out[i] = (s + b2[col]) * scale[col] + bias2[col];
}

extern "C" void kernel_launch(void* const* d_in, const int* in_sizes, int n_in,
                              void* d_out, int out_size, void* d_ws, size_t ws_size,
                              hipStream_t stream) {
    const float* x = (const float*)d_in[0];
    const float* cd1 = (const float*)d_in[1];
    const float* v1 = (const float*)d_in[2];
    const float* cd2 = (const float*)d_in[3];
    const float* v2 = (const float*)d_in[4];
    const float* W1 = (const float*)d_in[5];
    const float* b1 = (const float*)d_in[6];
    const float* W2 = (const float*)d_in[7];
    const float* b2 = (const float*)d_in[8];
    const float* out_scale = (const float*)d_in[9];
    const float* out_bias = (const float*)d_in[10];

    int I = in_sizes[1];
    int H = in_sizes[3];
    int O = in_sizes[8];
    int Bsz = out_size / O;
    int T = in_sizes[0] / (Bsz * I);
    const int ZSPLIT = 4;

    float* ws = (float*)d_ws;
    size_t off = 0;
    auto alloc = [&](size_t n) {
        size_t cur = off;
        off += (n + 63) & ~(size_t)63;
        return cur;
    };
    size_t o_df1 = alloc(I);
    size_t o_df2 = alloc(H);
    size_t o_tw = alloc(T);
    size_t o_p1 = alloc((size_t)Bsz * I);
    size_t o_p2 = alloc((size_t)Bsz * H);
    size_t o_acc2 = alloc((size_t)Bsz * H);
    size_t o_bcat = alloc((size_t)H * I);      // [H][2I] ushorts = H*I floats
    size_t o_part = alloc((size_t)ZSPLIT * Bsz * O);
    size_t persist = off;

    size_t wsFloats = ws_size / 4;
    size_t perStep = (size_t)Bsz * I / 2 + (size_t)Bsz * H + 128;
    int TC = 1;
    if (wsFloats > persist) {
        size_t tcMax = (wsFloats - persist) / perStep;
        TC = (int)(tcMax < (size_t)T ? tcMax : (size_t)T);
        if (TC < 1) TC = 1;
    }
    size_t o_s1 = alloc(((size_t)TC * Bsz * I + 1) / 2);
    size_t o_h = alloc((size_t)TC * Bsz * H);

    float* df1 = ws + o_df1;
    float* df2 = ws + o_df2;
    float* tw = ws + o_tw;
    float* p1 = ws + o_p1;
    float* p2 = ws + o_p2;
    float* acc2 = ws + o_acc2;
    ushort* bcat = (ushort*)(ws + o_bcat);
    float* part = ws + o_part;
    ushort* s1c = (ushort*)(ws + o_s1);
    float* hbuf = ws + o_h;

    k_init<<<2048, 256, 0, stream>>>(cd1, v1, cd2, v2, df1, df2, p1, p2, acc2, I, H,
                                     Bsz * I, Bsz * H);
    k_tw<<<1, 256, 0, stream>>>(v1, tw, T);
    k_wsplit<<<(H * I + 255) / 256, 256, 0, stream>>>(W1, bcat, H * I, I);

    for (int t0 = 0; t0 < T; t0 += TC) {
        int tc = (T - t0 < TC) ? (T - t0) : TC;
        k_lif1<<<(Bsz * I + 255) / 256, 256, 0, stream>>>(x, df1, p1, s1c, Bsz, T, I,
                                                          t0, tc);
        int Mrows = tc * Bsz;                  // tc*256 -> multiple of 256
        int gx = H / 256;
        int nwg = (Mrows / 256) * gx;          // tc*8 -> always %8==0
        k_gemm_mfma<<<nwg, 512, 0, stream>>>(s1c, bcat, b1, hbuf, H, I, gx);
        k_lif2<<<(Bsz * H + 255) / 256, 256, 0, stream>>>(hbuf, df2, tw, p2, acc2,
                                                          Bsz, H, t0, tc);
    }
    dim3 g2(O / 64, Bsz / 64, ZSPLIT);
    k_gemm64<<<g2, 256, 0, stream>>>(acc2, W2, part, Bsz, O, H, H / ZSPLIT);
    k_fin<<<(Bsz * O + 255) / 256, 256, 0, stream>>>(part, b2, out_scale, out_bias,
                                                     (float*)d_out, Bsz, O, ZSPLIT);
}